// Round 1
// 74.053 us; speedup vs baseline: 1.0830x; 1.0830x over previous
//
#include <hip/hip_runtime.h>

#define SEQ   512
#define BATCH 256
#define NH    7   // helper partial slots (waves 1..7)

// Uniform-index lane broadcast via v_readlane (index must be SGPR/imm).
__device__ __forceinline__ float bcast_f(float v, int srcLane) {
    return __int_as_float(__builtin_amdgcn_readlane(__float_as_int(v), srcLane));
}
// gfx950: v_log_f32 is log2, v_exp_f32 is exp2.
__device__ __forceinline__ float flog2(float x) { return __builtin_amdgcn_logf(x); }
__device__ __forceinline__ float fexp2(float x) { return __builtin_amdgcn_exp2f(x); }
// Barrier draining only LDS ops (lgkmcnt); __syncthreads() would also drain vmcnt.
__device__ __forceinline__ void lds_barrier() {
    __asm__ __volatile__("s_waitcnt lgkmcnt(0)\ns_barrier" ::: "memory");
}

// CNT-column contribution for one row block: rows in lanes, column scalars
// (p_k, xj_k) pre-extracted to wave-uniform registers (no readlane, no fma,
// no predicate in the inner loop). Two accumulators break the add chain.
template <int CNT>
__device__ __forceinline__ float row_terms(float xr,
                                           const float* __restrict__ pj,
                                           const float* __restrict__ xj) {
    float acc0 = 0.0f, acc1 = 0.0f;
#pragma unroll
    for (int k = 0; k < CNT; ++k) {
        const float L = flog2(fmaxf(xr - xj[k], 1.0f));
        const float t = fexp2(pj[k] * L);
        if (k & 1) acc1 += t; else acc0 += t;
    }
    return acc0 + acc1;
}

// Helper wave phase loop. start is SALU-uniform (from readfirstlane'd wid), so
// all readlane indices are SGPR-resident: no per-term v_readfirstlane/hazards.
template <int CNT>
__device__ __forceinline__ void run_helper(const int start, const int hidx,
                                           const int lane, const float a,
                                           const float c,
                                           float (&x_lds)[SEQ],
                                           float (&expm_lds)[SEQ],
                                           float (&part_lds)[NH][8][64]) {
    for (int J = 0; J < 8; ++J) {
        float pj[CNT], xj[CNT];
        if (J > 0) {
            // Column block J-1: extract this wave's CNT column scalars ONCE.
            const float evec = expm_lds[((J - 1) << 6) | lane];
            const float xv   = x_lds[((J - 1) << 6) | lane];
            const float pvec = -fmaf(c, evec, a);   // p for all 64 cols, 1 op
#pragma unroll
            for (int k = 0; k < CNT; ++k) {
                pj[k] = bcast_f(pvec, start + k);
                xj[k] = bcast_f(xv,   start + k);
            }
            // ---- panel: col block J-1 -> row block J (pre-barrier, serial path)
            const float prev = part_lds[hidx][J][lane];
            const float xr   = x_lds[(J << 6) | lane];
            const float t    = row_terms<CNT>(xr, pj, xj);
            part_lds[hidx][J][lane] = prev + t;
        }
        lds_barrier();  // B1: panel partials for row block J ready
        if (J > 0 && J < 7) {
            // ---- deep: col block J-1 -> row blocks J+1..7 (overlaps diagonal)
            for (int R = J + 1; R < 8; ++R) {
                const float prev = part_lds[hidx][R][lane];
                const float xr   = x_lds[(R << 6) | lane];
                const float t    = row_terms<CNT>(xr, pj, xj);
                part_lds[hidx][R][lane] = prev + t;
            }
        }
        lds_barrier();  // B2: expm block J published by wave0; deep writes done
    }
}

// Wave 0: merge + serial 64-step diagonal per phase. Maskless diag: lanes
// i <= jl give L=0 -> term=1.0 exactly; readlane at step jl precedes lane jl's
// first contamination; subtract (64-lane) once at publish.
__device__ __forceinline__ void run_diag(const int lane, const float a,
                                         const float c,
                                         float (&x_lds)[SEQ],
                                         float (&expm_lds)[SEQ],
                                         float (&part_lds)[NH][8][64]) {
    for (int J = 0; J < 8; ++J) {
        lds_barrier();  // B1: off-diagonal partials for row block J ready
        float acc = 0.0f;
#pragma unroll
        for (int hh = 0; hh < NH; ++hh) acc += part_lds[hh][J][lane];

        const float xd = x_lds[(J << 6) | lane];
#pragma unroll
        for (int jl = 0; jl < 64; ++jl) {
            const float sj  = bcast_f(xd, jl);               // off-chain (imm idx)
            const float L   = flog2(fmaxf(xd - sj, 1.0f));   // off-chain
            const float nAL = -a * L;                        // off-chain
            const float nCL = -c * L;                        // off-chain
            const float em  = bcast_f(acc, jl);              // chain
            acc += fexp2(fmaf(nCL, em, nAL));                // chain
        }
        expm_lds[(J << 6) | lane] = acc - (float)(64 - lane);  // publish clean
        lds_barrier();  // B2
    }
}

__global__ void __launch_bounds__(512, 1)
act_r_kernel(const float* __restrict__ sp, const float* __restrict__ w,
             float* __restrict__ out) {
    __shared__ float x_lds[SEQ];
    __shared__ float expm_lds[SEQ];
    __shared__ float part_lds[NH][8][64];   // [helper][row block][lane]

    const int b    = blockIdx.x;
    const int tid  = threadIdx.x;
    const int lane = tid & 63;
    // Wave id as a PROVEN-uniform SGPR value: everything derived from it
    // (role branch, start, readlane indices) stays SALU/SGPR.
    const int uwid = __builtin_amdgcn_readfirstlane(tid >> 6);

    const float a   = w[0];
    const float c   = w[1];
    const float s   = w[2];
    const float tau = w[3];
    const float h   = w[4];
    const float scale = 86400.0f * h;

    for (int k = tid; k < NH * 8 * 64; k += 512) ((float*)part_lds)[k] = 0.0f;
    x_lds[tid] = sp[tid * BATCH + b] * scale;
    lds_barrier();

    if (uwid == 0) {
        // Serial chain is the latency-critical path: favor wave0 on SIMD0
        // issue arbitration against co-resident wave4.
        __builtin_amdgcn_s_setprio(1);
        run_diag(lane, a, c, x_lds, expm_lds, part_lds);
        __builtin_amdgcn_s_setprio(0);
    } else if (uwid == 4) {
        // wave4 shares SIMD0 with wave0: smaller column share (cols 30..33).
        run_helper<4>(30, 3, lane, a, c, x_lds, expm_lds, part_lds);
    } else {
        // cols: w1:0-9 w2:10-19 w3:20-29 w5:34-43 w6:44-53 w7:54-63
        const int start = (uwid - 1) * 10 - ((uwid > 4) ? 6 : 0);
        run_helper<10>(start, uwid - 1, lane, a, c, x_lds, expm_lds, part_lds);
    }

    // ---- epilogue: all 512 threads, one output each (i = tid, skip 0)
    if (tid >= 1) {
        const float inv_ln2 = 1.4426950408889634f;
        const float q = tau / s * inv_ln2 - flog2(expm_lds[tid]) / s;
        out[(tid - 1) * BATCH + b] = 1.0f / (1.0f + fexp2(q));
    }
}

extern "C" void kernel_launch(void* const* d_in, const int* in_sizes, int n_in,
                              void* d_out, int out_size, void* d_ws, size_t ws_size,
                              hipStream_t stream) {
    const float* sp = (const float*)d_in[0];  // [512, 256, 1] f32
    const float* w  = (const float*)d_in[1];  // [5] f32
    float* out = (float*)d_out;               // [511, 256, 1] f32
    (void)in_sizes; (void)n_in; (void)out_size; (void)d_ws; (void)ws_size;

    act_r_kernel<<<dim3(BATCH), dim3(512), 0, stream>>>(sp, w, out);
}